// Round 1
// 72.755 us; speedup vs baseline: 1.0665x; 1.0665x over previous
//
#include <hip/hip_runtime.h>

// BEV orthographic 3D Gaussian splatting, B=2, N=1024, D=32, H=W=200.
// Single kernel: 8x8 tile per block, 4 waves/block, each wave composites a
// 256-gaussian segment (aligned to the reference's 128-chunks), combined via
// the associative operator (img1,T1)o(img2,T2) = (img1 + T1*img2, T1*T2).
//
// Round-N changes vs 77.5us version:
//  - NO barriers in the main loop: compaction arrays were wave-local ([wid]),
//    replaced by ballot-mask bit-scan + v_readlane broadcast (register-only).
//  - 1/det division only for bbox-passing gaussians; radius uses
//    lmax(cov2D) directly (lmin(conic) == 1/lmax(cov2D) for 2x2), no rcp.
//  - feats pointer now wave-uniform via SGPR index -> scalarizable loads.
//  - LDS 41KB -> 33KB: occupancy 3 -> 4 blocks/CU.
// Semantics identical: order = ballot bit order = input order; all surviving
// gaussians pass the exact (power>0, alpha>=1/255, eps-stop) tests.
// Output: [bev (2,32,200,200) | mean_count scalar].

#define HH 200
#define WW 200
#define DD 32
#define NG 1024
#define BB 2
#define OUT_IMG (BB*DD*HH*WW)   // 2560000
#define NW 4                    // waves per block = gaussian segments
#define SEGG (NG/NW)            // 256 gaussians per segment (= 2 ref chunks)
#define NGRP (SEGG/64)          // 4 ballot groups of 64

__device__ __forceinline__ float rlane(float x, int l) {
    return __uint_as_float(__builtin_amdgcn_readlane(__float_as_uint(x), l));
}

__global__ __launch_bounds__(64*NW, 4) void render_kernel(
    const float* __restrict__ feats,   // (B, NG, DD)
    const float* __restrict__ means,   // (B, NG, 3)
    const float* __restrict__ cov,     // (B, NG, 6)
    const float* __restrict__ opac,    // (B, NG)
    float* __restrict__ out)
{
    __shared__ float4 simg[NW][64][8];   // swizzled ch4 slot = (c4+px)&7
    __shared__ float sT[NW][64];
    __shared__ float wsum[NW];

    const int b    = blockIdx.z;
    const int tid  = threadIdx.x;
    const int lane = tid & 63;
    const int wid  = tid >> 6;
    const int px   = blockIdx.x*8 + (lane & 7);
    const int py   = blockIdx.y*8 + (lane >> 3);
    const float pxf = (float)px, pyf = (float)py;
    const float cx  = blockIdx.x*8 + 3.5f;
    const float cy  = blockIdx.y*8 + 3.5f;

    const float* __restrict__ featsB = feats + (size_t)b * NG * DD;
    const int gB = b * NG;

    float4 acc[8];
#pragma unroll
    for (int j = 0; j < 8; ++j) acc[j] = make_float4(0.f,0.f,0.f,0.f);
    float T = 1.f, P = 1.f;
    bool skip = false;

    for (int k = 0; k < NGRP; ++k) {
        const int gbase = wid*SEGG + k*64;       // segment-local base index
        const int g  = gB + gbase + lane;
        const float o   = opac[g];
        const float2 c01 = *(const float2*)(cov + (size_t)g*6);  // 24B-aligned
        const float c3  = cov[(size_t)g*6 + 3];
        const float av = 4.f*c3    + 0.3f;       // image-x variance
        const float cv = 4.f*c01.x + 0.3f;       // image-y variance
        const float bv = 4.f*c01.y;
        const float det = av*cv - bv*bv;
        bool flag = false;
        float u=0.f, v=0.f, A=0.f, Bc=0.f, Cc=0.f, pl=0.f;
        if (o > 0.05f && det > 0.f) {
            u = -2.f*means[(size_t)g*3+1] + 100.f;
            v = -2.f*means[(size_t)g*3+0] + 100.f;
            pl = -__logf(255.f*o);               // power floor for alpha>=1/255
            const float qmax = -2.f*pl;          // >0 since o>0.05
            const float htr = 0.5f*(av+cv), hdf = 0.5f*(av-cv);
            const float lmax = htr + sqrtf(hdf*hdf + bv*bv);  // lmax(cov2D)
            const float r = sqrtf(qmax*lmax) + 0.5f;          // == old radius
            if (fabsf(u - cx) <= 3.5f + r && fabsf(v - cy) <= 3.5f + r) {
                const float inv = 1.f/det;       // exact division, rare path
                A = cv*inv; Bc = bv*inv; Cc = av*inv;
                flag = true;
            }
        }
        unsigned long long mm = __ballot(flag);  // bit order == index order
        if (!skip) {
            while (mm) {
                const int i = (int)__builtin_ctzll(mm);
                mm &= mm - 1ull;
                const float ui  = rlane(u,  i);
                const float vi  = rlane(v,  i);
                const float Ai  = rlane(A,  i);
                const float Bi  = rlane(Bc, i);
                const float Ci  = rlane(Cc, i);
                const float oi  = rlane(o,  i);
                const float pli = rlane(pl, i);
                const float dx = ui - pxf;
                const float dy = vi - pyf;
                const float pw = fmaf(Bi, dx*dy, -0.5f*(Ai*dx*dx + Ci*dy*dy));
                if (pw > 0.f) continue;                    // reference mask
                if (pw < pli - 1e-3f) continue;            // provably alpha<1/255
                const float alpha = fminf(0.99f, oi * __expf(pw));
                if (alpha < (1.f/255.f)) continue;         // exact check
                const float om = 1.f - alpha;
                const float tp = T * P;
                if (tp * om < 1e-4f) { skip = true; break; }  // chunk eps-stop
                const float w = alpha * tp;
                const float4* __restrict__ col =           // wave-uniform addr
                    (const float4*)(featsB + (size_t)(gbase + i) * DD);
#pragma unroll
                for (int j = 0; j < 8; ++j) {
                    const float4 c4 = col[j];
                    acc[j].x = fmaf(w, c4.x, acc[j].x);
                    acc[j].y = fmaf(w, c4.y, acc[j].y);
                    acc[j].z = fmaf(w, c4.z, acc[j].z);
                    acc[j].w = fmaf(w, c4.w, acc[j].w);
                }
                P *= om;
            }
        }
        if (k & 1) { T *= P; P = 1.f; skip = false; }   // 128-chunk boundary
    }

    // ---- cross-wave combine: img = sum_s prefixT_s * img_s
    sT[wid][lane] = T * P;   // P==1 here (NGRP even), kept for clarity
#pragma unroll
    for (int j = 0; j < 8; ++j)
        simg[wid][lane][(j + lane) & 7] = acc[j];        // bank-swizzled
    __syncthreads();

    {
        const int p   = tid & 63;                        // pixel within tile
        const int grp = tid >> 6;                        // channel-quad pair
        const float t0 = sT[0][p], t1 = sT[1][p], t2 = sT[2][p];
        const float pf1 = t0, pf2 = t0*t1, pf3 = pf2*t2;
        const int ppx = blockIdx.x*8 + (p & 7);
        const int ppy = blockIdx.y*8 + (p >> 3);
        const size_t base = (size_t)b * DD * (HH*WW) + (size_t)ppy * WW + ppx;
#pragma unroll
        for (int q = 0; q < 2; ++q) {
            const int c4 = grp*2 + q;
            const int slot = (c4 + p) & 7;
            const float4 r0 = simg[0][p][slot];
            const float4 r1 = simg[1][p][slot];
            const float4 r2 = simg[2][p][slot];
            const float4 r3 = simg[3][p][slot];
            float4 ov;
            ov.x = fmaf(pf3, r3.x, fmaf(pf2, r2.x, fmaf(pf1, r1.x, r0.x)));
            ov.y = fmaf(pf3, r3.y, fmaf(pf2, r2.y, fmaf(pf1, r1.y, r0.y)));
            ov.z = fmaf(pf3, r3.z, fmaf(pf2, r2.z, fmaf(pf1, r1.z, r0.z)));
            ov.w = fmaf(pf3, r3.w, fmaf(pf2, r2.w, fmaf(pf1, r1.w, r0.w)));
            out[base + (size_t)(c4*4+0)*(HH*WW)] = ov.x;
            out[base + (size_t)(c4*4+1)*(HH*WW)] = ov.y;
            out[base + (size_t)(c4*4+2)*(HH*WW)] = ov.z;
            out[base + (size_t)(c4*4+3)*(HH*WW)] = ov.w;
        }
    }

    // ---- fused mean_count (one block)
    if (blockIdx.x == 0 && blockIdx.y == 0 && b == 0) {
        float s = 0.f;
        for (int i = tid; i < BB*NG; i += 64*NW)
            s += (opac[i] > 0.05f) ? 1.f : 0.f;
#pragma unroll
        for (int off = 32; off > 0; off >>= 1)
            s += __shfl_down(s, off, 64);
        if (lane == 0) wsum[wid] = s;
        __syncthreads();
        if (tid == 0)
            out[OUT_IMG] = (wsum[0]+wsum[1]+wsum[2]+wsum[3]) * (1.f/(float)BB);
    }
}

extern "C" void kernel_launch(void* const* d_in, const int* in_sizes, int n_in,
                              void* d_out, int out_size, void* d_ws, size_t ws_size,
                              hipStream_t stream) {
    const float* feats = (const float*)d_in[0];  // features (B,N,D)
    const float* means = (const float*)d_in[1];  // means3D  (B,N,3)
    const float* cvr   = (const float*)d_in[2];  // cov3D    (B,N,6)
    const float* opc   = (const float*)d_in[3];  // opacities(B,N,1)
    float* out = (float*)d_out;

    render_kernel<<<dim3(WW/8, HH/8, BB), dim3(64*NW), 0, stream>>>(
        feats, means, cvr, opc, out);
}